// Round 1
// baseline (83.426 us; speedup 1.0000x reference)
//
#include <hip/hip_runtime.h>
#include <hip/hip_bf16.h>
#include <stdint.h>

typedef __bf16 bf16_8 __attribute__((ext_vector_type(8)));
typedef float f32x4 __attribute__((ext_vector_type(4)));
typedef unsigned int u32;
typedef unsigned short u16;

// Problem dims (fixed): B=8, R=4, N=1024, D_IN=D_OUT=256.
// Inputs FP32 (per reference); internal GEMMs bf16 MFMA; output FP32.

__device__ __forceinline__ u16 f2b(float f) {
    return __builtin_bit_cast(u16, __float2bfloat16(f));
}

// LDS tile: 128 rows x 32 k (bf16) as 16B chunks, 4 chunks/row.
// Chunk (row,g) at index row*4 + (g ^ ((row>>1)&3)) -> frag reads (fixed g,
// 16 consecutive rows) stay <=2-way bank conflicted (free per m136).
__device__ __forceinline__ u32 swz_off(u32 row, u32 g) {
    return (row * 4u + (g ^ ((row >> 1) & 3u))) * 16u;
}

__device__ __forceinline__ void gload_lds16(const void* g, void* l) {
    __builtin_amdgcn_global_load_lds((const __attribute__((address_space(1))) void*)g,
                                     (__attribute__((address_space(3))) void*)l, 16, 0, 0);
}

__device__ __forceinline__ uint4 pack8(float4 a, float4 b) {
    uint4 pk;
    pk.x = (u32)f2b(a.x) | ((u32)f2b(a.y) << 16);
    pk.y = (u32)f2b(a.z) | ((u32)f2b(a.w) << 16);
    pk.z = (u32)f2b(b.x) | ((u32)f2b(b.y) << 16);
    pk.w = (u32)f2b(b.z) | ((u32)f2b(b.w) << 16);
    return pk;
}

// C[128x128] += A[128xK]*B[Kx128]; A row-major (k contig), B transposed
// (rows = n, k contig). 256 thr = 4 waves, 2x2 grid of 64x64 wave tiles.
// Pipelined 2-phase: stage tile ks+1 into LDS buf[c^1] (global_load_lds)
// BEFORE computing MFMAs on buf[c]; single counted-drain + raw barrier per
// step so load latency overlaps the MFMA phase. smem must be 32 KB.
template <int KSTEPS>
__device__ __forceinline__ void gemm_core(const u16* pA, u32 strideA,
                                          const u16* pB, u32 strideB,
                                          char* smem, f32x4 acc[4][4]) {
    const u32 t    = threadIdx.x;
    const u32 lane = t & 63u;
    const u32 w    = t >> 6;
    const u32 wm   = (w >> 1) * 64u;
    const u32 wn   = (w & 1u) * 64u;
    const u32 waveByte = (t & 192u) * 16u;           // wave-uniform LDS dst base
    const u32 row0 = t >> 2;
    const u32 gg0  = (t & 3u) ^ ((row0 >> 1) & 3u);
    const u32 row1 = row0 + 64u;
    const u32 gg1  = ((t + 256u) & 3u) ^ ((row1 >> 1) & 3u);
    const u32 fr = lane & 15u;
    const u32 fg = lane >> 4;

    // Prologue: stage tile 0 into buffer 0.
    gload_lds16(pA + (size_t)row0 * strideA + gg0 * 8u, smem + waveByte);
    gload_lds16(pA + (size_t)row1 * strideA + gg1 * 8u, smem + waveByte + 4096u);
    gload_lds16(pB + (size_t)row0 * strideB + gg0 * 8u, smem + 16384u + waveByte);
    gload_lds16(pB + (size_t)row1 * strideB + gg1 * 8u, smem + 16384u + waveByte + 4096u);
    asm volatile("s_waitcnt vmcnt(0)" ::: "memory");
    __builtin_amdgcn_s_barrier();

    u32 c = 0;
#pragma unroll 2
    for (int ks = 0; ks < KSTEPS; ++ks) {
        char* curA = smem + c * 8192u;
        char* curB = smem + 16384u + c * 8192u;
        if (ks + 1 < KSTEPS) {
            char* nxtA = smem + (c ^ 1u) * 8192u;
            char* nxtB = smem + 16384u + (c ^ 1u) * 8192u;
            const u32 k0 = (u32)(ks + 1) * 32u;
            gload_lds16(pA + (size_t)row0 * strideA + k0 + gg0 * 8u, nxtA + waveByte);
            gload_lds16(pA + (size_t)row1 * strideA + k0 + gg1 * 8u, nxtA + waveByte + 4096u);
            gload_lds16(pB + (size_t)row0 * strideB + k0 + gg0 * 8u, nxtB + waveByte);
            gload_lds16(pB + (size_t)row1 * strideB + k0 + gg1 * 8u, nxtB + waveByte + 4096u);
        }

        bf16_8 af[4], bfv[4];
#pragma unroll
        for (int mt = 0; mt < 4; ++mt) {
            uint4 v = *(const uint4*)(curA + swz_off(wm + (u32)mt * 16u + fr, fg));
            af[mt] = __builtin_bit_cast(bf16_8, v);
        }
#pragma unroll
        for (int nt = 0; nt < 4; ++nt) {
            uint4 v = *(const uint4*)(curB + swz_off(wn + (u32)nt * 16u + fr, fg));
            bfv[nt] = __builtin_bit_cast(bf16_8, v);
        }
#pragma unroll
        for (int mt = 0; mt < 4; ++mt)
#pragma unroll
            for (int nt = 0; nt < 4; ++nt)
                acc[mt][nt] = __builtin_amdgcn_mfma_f32_16x16x32_bf16(af[mt], bfv[nt],
                                                                      acc[mt][nt], 0, 0, 0);

        if (ks + 1 < KSTEPS) {
            // Drain staging loads for tile ks+1 (latency already overlapped
            // with the MFMAs above), then one barrier; buffers flip.
            asm volatile("s_waitcnt vmcnt(0)" ::: "memory");
            __builtin_amdgcn_s_barrier();
        }
        c ^= 1u;
    }
}

// textb = bf16(text), layout preserved [B,N,D_in]. 8 elems/thread.
__global__ __launch_bounds__(256) void text_cvt_kernel(const float* t, u16* tb) {
    const u32 i8 = blockIdx.x * 256u + threadIdx.x;  // 262144 total
    const float4 a = ((const float4*)t)[i8 * 2u];
    const float4 b = ((const float4*)t)[i8 * 2u + 1u];
    ((uint4*)tb)[i8] = pack8(a, b);
}

// Wt[r][dout][din] = bf16(W[r][din][dout])
__global__ __launch_bounds__(256) void wt_cvt_kernel(const float* W, u16* Wt) {
    const u32 idx = blockIdx.x * 256u + threadIdx.x;  // 262144 total
    const u32 r = idx >> 16, rem = idx & 65535u, dout = rem >> 8, din = rem & 255u;
    Wt[idx] = f2b(W[(r << 16) + (din << 8) + dout]);
}

// Yt[b,r,dout,j] = bf16( sum_din Wt[r,dout,din] * textb[b,j,din] )
__global__ __launch_bounds__(256) void y_gemm_kernel(const u16* Wt, const u16* textb,
                                                     u16* Yt) {
    __shared__ char smem[32768];
    const u32 bx = blockIdx.x;                 // 512 blocks: b(3)|r(2)|m(1)|n(3)
    const u32 n0 = (bx & 7u) * 128u;
    const u32 m0 = ((bx >> 3) & 1u) * 128u;
    const u32 r  = (bx >> 4) & 3u;
    const u32 b  = bx >> 6;
    const u16* pA = Wt + (size_t)r * 65536u + (size_t)m0 * 256u;
    const u16* pB = textb + (size_t)b * 262144u + (size_t)n0 * 256u;
    f32x4 acc[4][4];
#pragma unroll
    for (int i = 0; i < 4; ++i)
#pragma unroll
        for (int j = 0; j < 4; ++j) acc[i][j] = (f32x4){0.f, 0.f, 0.f, 0.f};
    gemm_core<8>(pA, 256u, pB, 256u, smem, acc);

    const u32 lane = threadIdx.x & 63u, w = threadIdx.x >> 6;
    const u32 wm = (w >> 1) * 64u, wn = (w & 1u) * 64u;
    const u32 rit = (lane >> 4) * 4u, cit = lane & 15u;  // C: row=(lane>>4)*4+reg
    u16* yb = Yt + (size_t)(b * 4u + r) * 262144u;
#pragma unroll
    for (int mt = 0; mt < 4; ++mt)
#pragma unroll
        for (int nt = 0; nt < 4; ++nt) {
            const u32 m = m0 + wm + (u32)mt * 16u + rit;
            const u32 n = n0 + wn + (u32)nt * 16u + cit;
#pragma unroll
            for (int rg = 0; rg < 4; ++rg)
                yb[(size_t)(m + (u32)rg) * 1024u + n] = f2b(acc[mt][nt][rg]);
        }
}

// Fused: partial[b,r,i,d] = inv[b,r,i] * sum_j adj[b,r,i,j]*Yt[b,r,d,j]
// where inv = 1/rowsum_fp32(adj row), computed in-block during staging.
// Pipelined 2-phase with double-buffered LDS:
//   stage tile ks+1 (B via global_load_lds into buf[c^1]; A via fp32 regs
//   loaded last iter -> bf16 pack -> ds_write into buf[c^1]) and issue A-reg
//   loads for tile ks+2, THEN run MFMAs on buf[c]; a single
//   vmcnt(0)+lgkmcnt(0) + raw s_barrier per step. All staging latency
//   overlaps the MFMA phase instead of serializing with it.
__global__ __launch_bounds__(256) void adj_gemm_fused(const float* adj, const u16* Yt,
                                                      float* partial) {
    __shared__ char smem[33280];
    // A bufs @ 0 / 8192, B bufs @ 16384 / 24576, sInv @ 32768
    float* sInv = (float*)(smem + 32768);

    const u32 bx = blockIdx.x;            // 512 blocks: b(3)|r(2)|i(3)|n(1)
    const u32 n0 = (bx & 1u) * 128u;
    const u32 m0 = ((bx >> 1) & 7u) * 128u;
    const u32 r  = (bx >> 4) & 3u;
    const u32 b  = bx >> 6;

    const float* pA = adj + (size_t)(b * 4u + r) * 1048576u + (size_t)m0 * 1024u;
    const u16*   pB = Yt + (size_t)(b * 4u + r) * 262144u + (size_t)n0 * 1024u;

    const u32 t    = threadIdx.x;
    const u32 lane = t & 63u;
    const u32 w    = t >> 6;
    const u32 wm   = (w >> 1) * 64u;
    const u32 wn   = (w & 1u) * 64u;
    const u32 waveByte = (t & 192u) * 16u;
    const u32 row0 = t >> 2;              // 0..63
    const u32 gg0  = (t & 3u) ^ ((row0 >> 1) & 3u);
    const u32 row1 = row0 + 64u;          // 64..127
    const u32 gg1  = ((t + 256u) & 3u) ^ ((row1 >> 1) & 3u);
    const u32 fr = lane & 15u;
    const u32 fg = lane >> 4;

    f32x4 acc[4][4];
#pragma unroll
    for (int i = 0; i < 4; ++i)
#pragma unroll
        for (int j = 0; j < 4; ++j) acc[i][j] = (f32x4){0.f, 0.f, 0.f, 0.f};

    const float* rp0 = pA + (size_t)row0 * 1024u + gg0 * 8u;
    const float* rp1 = pA + (size_t)row1 * 1024u + gg1 * 8u;

    float s0 = 0.f, s1 = 0.f;

    // ---- Prologue: stage tile 0 into buffer 0; prefetch A(1) regs. ----
    float4 a0 = *(const float4*)(rp0);
    float4 a1 = *(const float4*)(rp0 + 4);
    float4 a2 = *(const float4*)(rp1);
    float4 a3 = *(const float4*)(rp1 + 4);

    gload_lds16(pB + (size_t)row0 * 1024u + gg0 * 8u, smem + 16384u + waveByte);
    gload_lds16(pB + (size_t)row1 * 1024u + gg1 * 8u, smem + 16384u + waveByte + 4096u);
    s0 += (a0.x + a0.y + a0.z + a0.w) + (a1.x + a1.y + a1.z + a1.w);
    s1 += (a2.x + a2.y + a2.z + a2.w) + (a3.x + a3.y + a3.z + a3.w);
    *(uint4*)(smem + t * 16u) = pack8(a0, a1);
    *(uint4*)(smem + (t + 256u) * 16u) = pack8(a2, a3);

    a0 = *(const float4*)(rp0 + 32u);      // A(1) regs
    a1 = *(const float4*)(rp0 + 36u);
    a2 = *(const float4*)(rp1 + 32u);
    a3 = *(const float4*)(rp1 + 36u);

    asm volatile("s_waitcnt vmcnt(0) lgkmcnt(0)" ::: "memory");
    __builtin_amdgcn_s_barrier();

    u32 c = 0;
#pragma unroll 2
    for (int ks = 0; ks < 32; ++ks) {
        char* curA = smem + c * 8192u;
        char* curB = smem + 16384u + c * 8192u;

        if (ks < 31) {
            char* nxtA = smem + (c ^ 1u) * 8192u;
            char* nxtB = smem + 16384u + (c ^ 1u) * 8192u;
            const u32 k0 = (u32)(ks + 1) * 32u;    // tile ks+1
            gload_lds16(pB + (size_t)row0 * 1024u + k0 + gg0 * 8u, nxtB + waveByte);
            gload_lds16(pB + (size_t)row1 * 1024u + k0 + gg1 * 8u, nxtB + waveByte + 4096u);
            s0 += (a0.x + a0.y + a0.z + a0.w) + (a1.x + a1.y + a1.z + a1.w);
            s1 += (a2.x + a2.y + a2.z + a2.w) + (a3.x + a3.y + a3.z + a3.w);
            *(uint4*)(nxtA + t * 16u) = pack8(a0, a1);
            *(uint4*)(nxtA + (t + 256u) * 16u) = pack8(a2, a3);

            // Prefetch A(ks+2) regs — consumed at next iteration's ds_write;
            // latency overlaps the MFMAs below. Dummy k=0 load on last steps
            // keeps the code uniform (result unused).
            const u32 k2 = (ks < 30) ? (u32)(ks + 2) * 32u : 0u;
            a0 = *(const float4*)(rp0 + k2);
            a1 = *(const float4*)(rp0 + k2 + 4u);
            a2 = *(const float4*)(rp1 + k2);
            a3 = *(const float4*)(rp1 + k2 + 4u);
        }

        bf16_8 af[4], bfv[4];
#pragma unroll
        for (int mt = 0; mt < 4; ++mt) {
            uint4 v = *(const uint4*)(curA + swz_off(wm + (u32)mt * 16u + fr, fg));
            af[mt] = __builtin_bit_cast(bf16_8, v);
        }
#pragma unroll
        for (int nt = 0; nt < 4; ++nt) {
            uint4 v = *(const uint4*)(curB + swz_off(wn + (u32)nt * 16u + fr, fg));
            bfv[nt] = __builtin_bit_cast(bf16_8, v);
        }
#pragma unroll
        for (int mt = 0; mt < 4; ++mt)
#pragma unroll
            for (int nt = 0; nt < 4; ++nt)
                acc[mt][nt] = __builtin_amdgcn_mfma_f32_16x16x32_bf16(af[mt], bfv[nt],
                                                                      acc[mt][nt], 0, 0, 0);

        if (ks < 31) {
            asm volatile("s_waitcnt vmcnt(0) lgkmcnt(0)" ::: "memory");
            __builtin_amdgcn_s_barrier();
        }
        c ^= 1u;
    }

    // rowsum: 4 consecutive lanes (t&3) hold partials of the same row
    s0 += __shfl_down(s0, 2, 64); s0 += __shfl_down(s0, 1, 64);
    s1 += __shfl_down(s1, 2, 64); s1 += __shfl_down(s1, 1, 64);
    if ((t & 3u) == 0u) {
        sInv[row0] = (s0 == 0.f) ? 0.f : 1.f / s0;
        sInv[row1] = (s1 == 0.f) ? 0.f : 1.f / s1;
    }
    __syncthreads();

    const u32 rit = (lane >> 4) * 4u, cit = lane & 15u;
    float* pp = partial + (size_t)(b * 4u + r) * 262144u;
#pragma unroll
    for (int mt = 0; mt < 4; ++mt) {
        const u32 mBase = wm + (u32)mt * 16u + rit;
        float sv[4];
#pragma unroll
        for (int rg = 0; rg < 4; ++rg) sv[rg] = sInv[mBase + (u32)rg];
#pragma unroll
        for (int nt = 0; nt < 4; ++nt) {
            const u32 n = n0 + wn + (u32)nt * 16u + cit;
#pragma unroll
            for (int rg = 0; rg < 4; ++rg)
                pp[(size_t)(m0 + mBase + (u32)rg) * 256u + n] = acc[mt][nt][rg] * sv[rg];
        }
    }
}

// out[b,i,d] = bias[d] + sum_r partial[b,r,i,d]
__global__ __launch_bounds__(256) void reduce_kernel(const float* partial,
                                                     const float* bias, float* out) {
    const u32 i4 = blockIdx.x * 256u + threadIdx.x;  // 524288 threads, 4 f32 each
    const u32 base = i4 * 4u;
    const u32 b = base >> 18;
    const u32 rem = base & 262143u;
    float4 s = ((const float4*)bias)[i4 & 63u];
#pragma unroll
    for (u32 r = 0; r < 4; ++r) {
        const float4 v = *(const float4*)(partial + (((size_t)(b * 4u + r)) << 18) + rem);
        s.x += v.x; s.y += v.y; s.z += v.z; s.w += v.w;
    }
    ((float4*)out)[i4] = s;
}

extern "C" void kernel_launch(void* const* d_in, const int* in_sizes, int n_in,
                              void* d_out, int out_size, void* d_ws, size_t ws_size,
                              hipStream_t stream) {
    const float* text = (const float*)d_in[0];  // [8,1024,256] fp32
    const float* adj  = (const float*)d_in[1];  // [8,4,1024,1024] fp32
    const float* wgt  = (const float*)d_in[2];  // [4,256,256] fp32
    const float* bias = (const float*)d_in[3];  // [256] fp32
    float* out = (float*)d_out;                 // [8,1024,256] fp32

    char* ws = (char*)d_ws;
    u16* Yt        = (u16*)ws;                      // 16 MB  bf16 [B,R,256,1024]
    u16* textb     = (u16*)(ws + 16777216u);        //  4 MB  bf16 [B,N,256]
    u16* Wt        = (u16*)(ws + 20971520u);        // 512 KB bf16 [R,256,256]
    float* partial = (float*)(ws + 21495808u);      // 32 MB  fp32 [B,R,N,256]

    text_cvt_kernel<<<1024, 256, 0, stream>>>(text, textb);
    wt_cvt_kernel<<<1024, 256, 0, stream>>>(wgt, Wt);
    y_gemm_kernel<<<512, 256, 0, stream>>>(Wt, textb, Yt);
    adj_gemm_fused<<<512, 256, 0, stream>>>(adj, Yt, partial);
    reduce_kernel<<<2048, 256, 0, stream>>>(partial, bias, out);
}

// Round 2
// 70.108 us; speedup vs baseline: 1.1900x; 1.1900x over previous
//
#include <hip/hip_runtime.h>
#include <hip/hip_bf16.h>
#include <stdint.h>

typedef __bf16 bf16_8 __attribute__((ext_vector_type(8)));
typedef float f32x4 __attribute__((ext_vector_type(4)));
typedef unsigned int u32;
typedef unsigned short u16;

// Problem dims (fixed): B=8, R=4, N=1024, D_IN=D_OUT=256.
// Inputs FP32 (per reference); internal GEMMs bf16 MFMA; output FP32.

__device__ __forceinline__ u16 f2b(float f) {
    return __builtin_bit_cast(u16, __float2bfloat16(f));
}

// LDS tile: 128 rows x 32 k (bf16) as 16B chunks, 4 chunks/row.
// Chunk (row,g) at index row*4 + (g ^ ((row>>1)&3)) -> frag reads (fixed g,
// 16 consecutive rows) stay <=2-way bank conflicted (free per m136).
__device__ __forceinline__ u32 swz_off(u32 row, u32 g) {
    return (row * 4u + (g ^ ((row >> 1) & 3u))) * 16u;
}

__device__ __forceinline__ void gload_lds16(const void* g, void* l) {
    __builtin_amdgcn_global_load_lds((const __attribute__((address_space(1))) void*)g,
                                     (__attribute__((address_space(3))) void*)l, 16, 0, 0);
}

// Compiler-only memory scheduling fence: pins VMEM issue-order regions so
// counted s_waitcnt vmcnt(N) bookkeeping is deterministic.
__device__ __forceinline__ void memfence_sched() { asm volatile("" ::: "memory"); }

__device__ __forceinline__ uint4 pack8(float4 a, float4 b) {
    uint4 pk;
    pk.x = (u32)f2b(a.x) | ((u32)f2b(a.y) << 16);
    pk.y = (u32)f2b(a.z) | ((u32)f2b(a.w) << 16);
    pk.z = (u32)f2b(b.x) | ((u32)f2b(b.y) << 16);
    pk.w = (u32)f2b(b.z) | ((u32)f2b(b.w) << 16);
    return pk;
}

// C[128x128] += A[128xK]*B[Kx128]; A row-major (k contig), B transposed
// (rows = n, k contig). 256 thr = 4 waves, 2x2 grid of 64x64 wave tiles.
// 2-phase pipelined (y_gemm is ~3 us; not the bottleneck). smem = 32 KB.
template <int KSTEPS>
__device__ __forceinline__ void gemm_core(const u16* pA, u32 strideA,
                                          const u16* pB, u32 strideB,
                                          char* smem, f32x4 acc[4][4]) {
    const u32 t    = threadIdx.x;
    const u32 lane = t & 63u;
    const u32 w    = t >> 6;
    const u32 wm   = (w >> 1) * 64u;
    const u32 wn   = (w & 1u) * 64u;
    const u32 waveByte = (t & 192u) * 16u;           // wave-uniform LDS dst base
    const u32 row0 = t >> 2;
    const u32 gg0  = (t & 3u) ^ ((row0 >> 1) & 3u);
    const u32 row1 = row0 + 64u;
    const u32 gg1  = ((t + 256u) & 3u) ^ ((row1 >> 1) & 3u);
    const u32 fr = lane & 15u;
    const u32 fg = lane >> 4;

    gload_lds16(pA + (size_t)row0 * strideA + gg0 * 8u, smem + waveByte);
    gload_lds16(pA + (size_t)row1 * strideA + gg1 * 8u, smem + waveByte + 4096u);
    gload_lds16(pB + (size_t)row0 * strideB + gg0 * 8u, smem + 16384u + waveByte);
    gload_lds16(pB + (size_t)row1 * strideB + gg1 * 8u, smem + 16384u + waveByte + 4096u);
    asm volatile("s_waitcnt vmcnt(0)" ::: "memory");
    __builtin_amdgcn_s_barrier();

    u32 c = 0;
#pragma unroll 2
    for (int ks = 0; ks < KSTEPS; ++ks) {
        char* curA = smem + c * 8192u;
        char* curB = smem + 16384u + c * 8192u;
        if (ks + 1 < KSTEPS) {
            char* nxtA = smem + (c ^ 1u) * 8192u;
            char* nxtB = smem + 16384u + (c ^ 1u) * 8192u;
            const u32 k0 = (u32)(ks + 1) * 32u;
            gload_lds16(pA + (size_t)row0 * strideA + k0 + gg0 * 8u, nxtA + waveByte);
            gload_lds16(pA + (size_t)row1 * strideA + k0 + gg1 * 8u, nxtA + waveByte + 4096u);
            gload_lds16(pB + (size_t)row0 * strideB + k0 + gg0 * 8u, nxtB + waveByte);
            gload_lds16(pB + (size_t)row1 * strideB + k0 + gg1 * 8u, nxtB + waveByte + 4096u);
        }

        bf16_8 af[4], bfv[4];
#pragma unroll
        for (int mt = 0; mt < 4; ++mt) {
            uint4 v = *(const uint4*)(curA + swz_off(wm + (u32)mt * 16u + fr, fg));
            af[mt] = __builtin_bit_cast(bf16_8, v);
        }
#pragma unroll
        for (int nt = 0; nt < 4; ++nt) {
            uint4 v = *(const uint4*)(curB + swz_off(wn + (u32)nt * 16u + fr, fg));
            bfv[nt] = __builtin_bit_cast(bf16_8, v);
        }
#pragma unroll
        for (int mt = 0; mt < 4; ++mt)
#pragma unroll
            for (int nt = 0; nt < 4; ++nt)
                acc[mt][nt] = __builtin_amdgcn_mfma_f32_16x16x32_bf16(af[mt], bfv[nt],
                                                                      acc[mt][nt], 0, 0, 0);

        if (ks + 1 < KSTEPS) {
            asm volatile("s_waitcnt vmcnt(0)" ::: "memory");
            __builtin_amdgcn_s_barrier();
        }
        c ^= 1u;
    }
}

// textb = bf16(text), layout preserved [B,N,D_in]. 8 elems/thread.
__global__ __launch_bounds__(256) void text_cvt_kernel(const float* t, u16* tb) {
    const u32 i8 = blockIdx.x * 256u + threadIdx.x;  // 262144 total
    const float4 a = ((const float4*)t)[i8 * 2u];
    const float4 b = ((const float4*)t)[i8 * 2u + 1u];
    ((uint4*)tb)[i8] = pack8(a, b);
}

// Wt[r][dout][din] = bf16(W[r][din][dout])
__global__ __launch_bounds__(256) void wt_cvt_kernel(const float* W, u16* Wt) {
    const u32 idx = blockIdx.x * 256u + threadIdx.x;  // 262144 total
    const u32 r = idx >> 16, rem = idx & 65535u, dout = rem >> 8, din = rem & 255u;
    Wt[idx] = f2b(W[(r << 16) + (din << 8) + dout]);
}

// Yt[b,r,dout,j] = bf16( sum_din Wt[r,dout,din] * textb[b,j,din] )
__global__ __launch_bounds__(256) void y_gemm_kernel(const u16* Wt, const u16* textb,
                                                     u16* Yt) {
    __shared__ char smem[32768];
    const u32 bx = blockIdx.x;                 // 512 blocks: b(3)|r(2)|m(1)|n(3)
    const u32 n0 = (bx & 7u) * 128u;
    const u32 m0 = ((bx >> 3) & 1u) * 128u;
    const u32 r  = (bx >> 4) & 3u;
    const u32 b  = bx >> 6;
    const u16* pA = Wt + (size_t)r * 65536u + (size_t)m0 * 256u;
    const u16* pB = textb + (size_t)b * 262144u + (size_t)n0 * 256u;
    f32x4 acc[4][4];
#pragma unroll
    for (int i = 0; i < 4; ++i)
#pragma unroll
        for (int j = 0; j < 4; ++j) acc[i][j] = (f32x4){0.f, 0.f, 0.f, 0.f};
    gemm_core<8>(pA, 256u, pB, 256u, smem, acc);

    const u32 lane = threadIdx.x & 63u, w = threadIdx.x >> 6;
    const u32 wm = (w >> 1) * 64u, wn = (w & 1u) * 64u;
    const u32 rit = (lane >> 4) * 4u, cit = lane & 15u;  // C: row=(lane>>4)*4+reg
    u16* yb = Yt + (size_t)(b * 4u + r) * 262144u;
#pragma unroll
    for (int mt = 0; mt < 4; ++mt)
#pragma unroll
        for (int nt = 0; nt < 4; ++nt) {
            const u32 m = m0 + wm + (u32)mt * 16u + rit;
            const u32 n = n0 + wn + (u32)nt * 16u + cit;
#pragma unroll
            for (int rg = 0; rg < 4; ++rg)
                yb[(size_t)(m + (u32)rg) * 1024u + n] = f2b(acc[mt][nt][rg]);
        }
}

// Fused: partial[b,r,i,d] = inv[b,r,i] * sum_j adj[b,r,i,j]*Yt[b,r,d,j]
// where inv = 1/rowsum_fp32(adj row), computed during staging.
//
// Depth-2 counted-vmcnt pipeline (T3/T4): per steady-state iteration ks,
// exactly 6 VMEM ops are issued (4x A float4 for tile ks+2, 2x B
// global_load_lds for tile ks+2); the end-of-iter wait is
// s_waitcnt vmcnt(6) — i.e. drain everything EXCEPT this iteration's 6 —
// so the previous iteration's loads (tile ks+1) are guaranteed landed and
// this iteration's loads stay in flight across the barrier. The memory
// queue never empties; no drain-to-0 in the main loop.
// Invariant entering iter ks: LDS has A(ks) [bufA ks&1] and B(ks)
// [bufB ks%3]; regs rA[(ks+1)&1] hold A(ks+1); outstanding VMEM =
// {A(ks+1) x4 (already landed or nearly), B(ks+1) x2} = 6.
__global__ __launch_bounds__(256) void adj_gemm_fused(const float* adj, const u16* Yt,
                                                      float* partial) {
    __shared__ char smem[41472];
    // bufA[2] @ 0, 8192 ; bufB[3] @ 16384, 24576, 32768 ; sInv @ 40960
    float* sInv = (float*)(smem + 40960);

    // XCD-contiguous bijective remap (512 = 8 XCDs x 64): n-pair blocks and
    // m-neighbors sharing adj/Yt panels co-reside on one XCD's L2.
    const u32 bxRaw = blockIdx.x;
    const u32 bx = (bxRaw & 7u) * 64u + (bxRaw >> 3);

    const u32 n0 = (bx & 1u) * 128u;
    const u32 m0 = ((bx >> 1) & 7u) * 128u;
    const u32 r  = (bx >> 4) & 3u;
    const u32 b  = bx >> 6;

    const float* pA = adj + (size_t)(b * 4u + r) * 1048576u + (size_t)m0 * 1024u;
    const u16*   pB = Yt + (size_t)(b * 4u + r) * 262144u + (size_t)n0 * 1024u;

    const u32 t    = threadIdx.x;
    const u32 lane = t & 63u;
    const u32 w    = t >> 6;
    const u32 wm   = (w >> 1) * 64u;
    const u32 wn   = (w & 1u) * 64u;
    const u32 waveByte = (t & 192u) * 16u;
    const u32 row0 = t >> 2;              // 0..63
    const u32 gg0  = (t & 3u) ^ ((row0 >> 1) & 3u);
    const u32 row1 = row0 + 64u;          // 64..127
    const u32 gg1  = ((t + 256u) & 3u) ^ ((row1 >> 1) & 3u);
    const u32 fr = lane & 15u;
    const u32 fg = lane >> 4;

    f32x4 acc[4][4];
#pragma unroll
    for (int i = 0; i < 4; ++i)
#pragma unroll
        for (int j = 0; j < 4; ++j) acc[i][j] = (f32x4){0.f, 0.f, 0.f, 0.f};

    const float* rp0 = pA + (size_t)row0 * 1024u + gg0 * 8u;
    const float* rp1 = pA + (size_t)row1 * 1024u + gg1 * 8u;

    float s0 = 0.f, s1 = 0.f;
    float4 rA[2][4];   // two A register sets; indices fold under unroll

    auto do_mfma = [&](char* curA, char* curB) {
        bf16_8 af[4], bfv[4];
#pragma unroll
        for (int mt = 0; mt < 4; ++mt) {
            uint4 v = *(const uint4*)(curA + swz_off(wm + (u32)mt * 16u + fr, fg));
            af[mt] = __builtin_bit_cast(bf16_8, v);
        }
#pragma unroll
        for (int nt = 0; nt < 4; ++nt) {
            uint4 v = *(const uint4*)(curB + swz_off(wn + (u32)nt * 16u + fr, fg));
            bfv[nt] = __builtin_bit_cast(bf16_8, v);
        }
#pragma unroll
        for (int mt = 0; mt < 4; ++mt)
#pragma unroll
            for (int nt = 0; nt < 4; ++nt)
                acc[mt][nt] = __builtin_amdgcn_mfma_f32_16x16x32_bf16(af[mt], bfv[nt],
                                                                      acc[mt][nt], 0, 0, 0);
    };
    auto pack_to = [&](const float4* rs, char* dst) {
        const float4 a0 = rs[0], a1 = rs[1], a2 = rs[2], a3 = rs[3];
        s0 += (a0.x + a0.y + a0.z + a0.w) + (a1.x + a1.y + a1.z + a1.w);
        s1 += (a2.x + a2.y + a2.z + a2.w) + (a3.x + a3.y + a3.z + a3.w);
        *(uint4*)(dst + t * 16u) = pack8(a0, a1);
        *(uint4*)(dst + (t + 256u) * 16u) = pack8(a2, a3);
    };

    // ---- Prologue ----
    // Group 1: A(0) -> rA[0], B(0) -> bufB0      (6 ops, oldest)
    rA[0][0] = *(const float4*)(rp0);
    rA[0][1] = *(const float4*)(rp0 + 4);
    rA[0][2] = *(const float4*)(rp1);
    rA[0][3] = *(const float4*)(rp1 + 4);
    gload_lds16(pB + (size_t)row0 * 1024u + gg0 * 8u, smem + 16384u + waveByte);
    gload_lds16(pB + (size_t)row1 * 1024u + gg1 * 8u, smem + 16384u + waveByte + 4096u);
    memfence_sched();
    // Group 2: A(1) -> rA[1], B(1) -> bufB1      (6 ops, newest)
    rA[1][0] = *(const float4*)(rp0 + 32u);
    rA[1][1] = *(const float4*)(rp0 + 36u);
    rA[1][2] = *(const float4*)(rp1 + 32u);
    rA[1][3] = *(const float4*)(rp1 + 36u);
    gload_lds16(pB + (size_t)row0 * 1024u + 32u + gg0 * 8u, smem + 24576u + waveByte);
    gload_lds16(pB + (size_t)row1 * 1024u + 32u + gg1 * 8u, smem + 24576u + waveByte + 4096u);
    memfence_sched();
    // Pack A(0) -> bufA0 (compiler-inserted wait drains A(0) loads).
    pack_to(rA[0], smem);
    // Drain B(0) too: keep only the newest 6 (= group 2) outstanding.
    asm volatile("s_waitcnt vmcnt(6) lgkmcnt(0)" ::: "memory");
    __builtin_amdgcn_s_barrier();

    // ---- Main loop: iterations 0..29 (tiles ks; issue tiles ks+2) ----
#pragma unroll 6
    for (int ks = 0; ks < 30; ++ks) {
        const int cA = ks & 1;         // folds under unroll (6j+c parity)
        const int nA = cA ^ 1;
        char* bufAc = smem + (u32)cA * 8192u;
        char* bufAn = smem + (u32)nA * 8192u;
        char* bufBc = smem + 16384u + (u32)(ks % 3) * 8192u;
        char* bufBn = smem + 16384u + (u32)((ks + 2) % 3) * 8192u;

        // Pack A(ks+1) (regs landed; compiler wait leaves B(ks+1) in flight).
        pack_to(rA[nA], bufAn);

        // Issue tile ks+2: 4x A float4 + 2x B gload_lds  (exactly 6 VMEM ops).
        const u32 k2 = (u32)(ks + 2) * 32u;
        rA[cA][0] = *(const float4*)(rp0 + k2);
        rA[cA][1] = *(const float4*)(rp0 + k2 + 4u);
        rA[cA][2] = *(const float4*)(rp1 + k2);
        rA[cA][3] = *(const float4*)(rp1 + k2 + 4u);
        gload_lds16(pB + (size_t)row0 * 1024u + k2 + gg0 * 8u, bufBn + waveByte);
        gload_lds16(pB + (size_t)row1 * 1024u + k2 + gg1 * 8u, bufBn + waveByte + 4096u);

        // Compute tile ks while ks+2's loads fly.
        do_mfma(bufAc, bufBc);

        // Drain everything except this iter's 6 ops -> B(ks+1) landed,
        // A ds_writes visible; tile ks+2's loads stay in flight.
        asm volatile("s_waitcnt vmcnt(6) lgkmcnt(0)" ::: "memory");
        __builtin_amdgcn_s_barrier();
    }

    // ---- Peeled iter 30: pack A(31), no new issues ----
    pack_to(rA[1], smem + 8192u);            // A(31) -> bufA1
    do_mfma(smem + 0u, smem + 16384u);       // tile 30: bufA0, bufB[30%3=0]
    asm volatile("s_waitcnt vmcnt(0) lgkmcnt(0)" ::: "memory");  // drain B(31)
    __builtin_amdgcn_s_barrier();

    // ---- Peeled iter 31 ----
    do_mfma(smem + 8192u, smem + 24576u);    // tile 31: bufA1, bufB[31%3=1]

    // rowsum: 4 consecutive lanes (t&3) hold partials of the same row
    s0 += __shfl_down(s0, 2, 64); s0 += __shfl_down(s0, 1, 64);
    s1 += __shfl_down(s1, 2, 64); s1 += __shfl_down(s1, 1, 64);
    if ((t & 3u) == 0u) {
        sInv[row0] = (s0 == 0.f) ? 0.f : 1.f / s0;
        sInv[row1] = (s1 == 0.f) ? 0.f : 1.f / s1;
    }
    __syncthreads();

    const u32 rit = (lane >> 4) * 4u, cit = lane & 15u;
    float* pp = partial + (size_t)(b * 4u + r) * 262144u;
#pragma unroll
    for (int mt = 0; mt < 4; ++mt) {
        const u32 mBase = wm + (u32)mt * 16u + rit;
        float sv[4];
#pragma unroll
        for (int rg = 0; rg < 4; ++rg) sv[rg] = sInv[mBase + (u32)rg];
#pragma unroll
        for (int nt = 0; nt < 4; ++nt) {
            const u32 n = n0 + wn + (u32)nt * 16u + cit;
#pragma unroll
            for (int rg = 0; rg < 4; ++rg)
                pp[(size_t)(m0 + mBase + (u32)rg) * 256u + n] = acc[mt][nt][rg] * sv[rg];
        }
    }
}

// out[b,i,d] = bias[d] + sum_r partial[b,r,i,d]
__global__ __launch_bounds__(256) void reduce_kernel(const float* partial,
                                                     const float* bias, float* out) {
    const u32 i4 = blockIdx.x * 256u + threadIdx.x;  // 524288 threads, 4 f32 each
    const u32 base = i4 * 4u;
    const u32 b = base >> 18;
    const u32 rem = base & 262143u;
    float4 s = ((const float4*)bias)[i4 & 63u];
#pragma unroll
    for (u32 r = 0; r < 4; ++r) {
        const float4 v = *(const float4*)(partial + (((size_t)(b * 4u + r)) << 18) + rem);
        s.x += v.x; s.y += v.y; s.z += v.z; s.w += v.w;
    }
    ((float4*)out)[i4] = s;
}

extern "C" void kernel_launch(void* const* d_in, const int* in_sizes, int n_in,
                              void* d_out, int out_size, void* d_ws, size_t ws_size,
                              hipStream_t stream) {
    const float* text = (const float*)d_in[0];  // [8,1024,256] fp32
    const float* adj  = (const float*)d_in[1];  // [8,4,1024,1024] fp32
    const float* wgt  = (const float*)d_in[2];  // [4,256,256] fp32
    const float* bias = (const float*)d_in[3];  // [256] fp32
    float* out = (float*)d_out;                 // [8,1024,256] fp32

    char* ws = (char*)d_ws;
    u16* Yt        = (u16*)ws;                      // 16 MB  bf16 [B,R,256,1024]
    u16* textb     = (u16*)(ws + 16777216u);        //  4 MB  bf16 [B,N,256]
    u16* Wt        = (u16*)(ws + 20971520u);        // 512 KB bf16 [R,256,256]
    float* partial = (float*)(ws + 21495808u);      // 32 MB  fp32 [B,R,N,256]

    text_cvt_kernel<<<1024, 256, 0, stream>>>(text, textb);
    wt_cvt_kernel<<<1024, 256, 0, stream>>>(wgt, Wt);
    y_gemm_kernel<<<512, 256, 0, stream>>>(Wt, textb, Yt);
    adj_gemm_fused<<<512, 256, 0, stream>>>(adj, Yt, partial);
    reduce_kernel<<<2048, 256, 0, stream>>>(partial, bias, out);
}

// Round 3
// 68.423 us; speedup vs baseline: 1.2193x; 1.0246x over previous
//
#include <hip/hip_runtime.h>
#include <hip/hip_bf16.h>
#include <stdint.h>

typedef __bf16 bf16_8 __attribute__((ext_vector_type(8)));
typedef float f32x4 __attribute__((ext_vector_type(4)));
typedef unsigned int u32;
typedef unsigned short u16;

// Problem dims (fixed): B=8, R=4, N=1024, D_IN=D_OUT=256.
// Inputs FP32 (per reference); internal GEMMs bf16 MFMA; output FP32.

__device__ __forceinline__ u16 f2b(float f) {
    return __builtin_bit_cast(u16, __float2bfloat16(f));
}

// LDS tile: rows x 32 k (bf16) as 16B chunks, 4 chunks/row.
// Chunk (row,g) at index row*4 + (g ^ ((row>>1)&3)) -> frag reads (fixed g,
// 16 consecutive rows) stay <=2-way bank conflicted (free per m136).
__device__ __forceinline__ u32 swz_off(u32 row, u32 g) {
    return (row * 4u + (g ^ ((row >> 1) & 3u))) * 16u;
}

__device__ __forceinline__ void gload_lds16(const void* g, void* l) {
    __builtin_amdgcn_global_load_lds((const __attribute__((address_space(1))) void*)g,
                                     (__attribute__((address_space(3))) void*)l, 16, 0, 0);
}

// Compiler-only memory scheduling fence: pins VMEM issue-order regions so
// counted s_waitcnt vmcnt(N) bookkeeping is deterministic.
__device__ __forceinline__ void memfence_sched() { asm volatile("" ::: "memory"); }

__device__ __forceinline__ uint4 pack8(float4 a, float4 b) {
    uint4 pk;
    pk.x = (u32)f2b(a.x) | ((u32)f2b(a.y) << 16);
    pk.y = (u32)f2b(a.z) | ((u32)f2b(a.w) << 16);
    pk.z = (u32)f2b(b.x) | ((u32)f2b(b.y) << 16);
    pk.w = (u32)f2b(b.z) | ((u32)f2b(b.w) << 16);
    return pk;
}

// C[128x128] += A[128xK]*B[Kx128]; A row-major (k contig), B transposed
// (rows = n, k contig). 256 thr = 4 waves, 2x2 grid of 64x64 wave tiles.
// 2-phase pipelined (y_gemm is ~3 us; not the bottleneck). smem = 32 KB.
template <int KSTEPS>
__device__ __forceinline__ void gemm_core(const u16* pA, u32 strideA,
                                          const u16* pB, u32 strideB,
                                          char* smem, f32x4 acc[4][4]) {
    const u32 t    = threadIdx.x;
    const u32 lane = t & 63u;
    const u32 w    = t >> 6;
    const u32 wm   = (w >> 1) * 64u;
    const u32 wn   = (w & 1u) * 64u;
    const u32 waveByte = (t & 192u) * 16u;           // wave-uniform LDS dst base
    const u32 row0 = t >> 2;
    const u32 gg0  = (t & 3u) ^ ((row0 >> 1) & 3u);
    const u32 row1 = row0 + 64u;
    const u32 gg1  = ((t + 256u) & 3u) ^ ((row1 >> 1) & 3u);
    const u32 fr = lane & 15u;
    const u32 fg = lane >> 4;

    gload_lds16(pA + (size_t)row0 * strideA + gg0 * 8u, smem + waveByte);
    gload_lds16(pA + (size_t)row1 * strideA + gg1 * 8u, smem + waveByte + 4096u);
    gload_lds16(pB + (size_t)row0 * strideB + gg0 * 8u, smem + 16384u + waveByte);
    gload_lds16(pB + (size_t)row1 * strideB + gg1 * 8u, smem + 16384u + waveByte + 4096u);
    asm volatile("s_waitcnt vmcnt(0)" ::: "memory");
    __builtin_amdgcn_s_barrier();

    u32 c = 0;
#pragma unroll 2
    for (int ks = 0; ks < KSTEPS; ++ks) {
        char* curA = smem + c * 8192u;
        char* curB = smem + 16384u + c * 8192u;
        if (ks + 1 < KSTEPS) {
            char* nxtA = smem + (c ^ 1u) * 8192u;
            char* nxtB = smem + 16384u + (c ^ 1u) * 8192u;
            const u32 k0 = (u32)(ks + 1) * 32u;
            gload_lds16(pA + (size_t)row0 * strideA + k0 + gg0 * 8u, nxtA + waveByte);
            gload_lds16(pA + (size_t)row1 * strideA + k0 + gg1 * 8u, nxtA + waveByte + 4096u);
            gload_lds16(pB + (size_t)row0 * strideB + k0 + gg0 * 8u, nxtB + waveByte);
            gload_lds16(pB + (size_t)row1 * strideB + k0 + gg1 * 8u, nxtB + waveByte + 4096u);
        }

        bf16_8 af[4], bfv[4];
#pragma unroll
        for (int mt = 0; mt < 4; ++mt) {
            uint4 v = *(const uint4*)(curA + swz_off(wm + (u32)mt * 16u + fr, fg));
            af[mt] = __builtin_bit_cast(bf16_8, v);
        }
#pragma unroll
        for (int nt = 0; nt < 4; ++nt) {
            uint4 v = *(const uint4*)(curB + swz_off(wn + (u32)nt * 16u + fr, fg));
            bfv[nt] = __builtin_bit_cast(bf16_8, v);
        }
#pragma unroll
        for (int mt = 0; mt < 4; ++mt)
#pragma unroll
            for (int nt = 0; nt < 4; ++nt)
                acc[mt][nt] = __builtin_amdgcn_mfma_f32_16x16x32_bf16(af[mt], bfv[nt],
                                                                      acc[mt][nt], 0, 0, 0);

        if (ks + 1 < KSTEPS) {
            asm volatile("s_waitcnt vmcnt(0)" ::: "memory");
            __builtin_amdgcn_s_barrier();
        }
        c ^= 1u;
    }
}

// textb = bf16(text), layout preserved [B,N,D_in]. 8 elems/thread.
__global__ __launch_bounds__(256) void text_cvt_kernel(const float* t, u16* tb) {
    const u32 i8 = blockIdx.x * 256u + threadIdx.x;  // 262144 total
    const float4 a = ((const float4*)t)[i8 * 2u];
    const float4 b = ((const float4*)t)[i8 * 2u + 1u];
    ((uint4*)tb)[i8] = pack8(a, b);
}

// Wt[r][dout][din] = bf16(W[r][din][dout])
__global__ __launch_bounds__(256) void wt_cvt_kernel(const float* W, u16* Wt) {
    const u32 idx = blockIdx.x * 256u + threadIdx.x;  // 262144 total
    const u32 r = idx >> 16, rem = idx & 65535u, dout = rem >> 8, din = rem & 255u;
    Wt[idx] = f2b(W[(r << 16) + (din << 8) + dout]);
}

// Yt[b,r,dout,j] = bf16( sum_din Wt[r,dout,din] * textb[b,j,din] )
__global__ __launch_bounds__(256) void y_gemm_kernel(const u16* Wt, const u16* textb,
                                                     u16* Yt) {
    __shared__ char smem[32768];
    const u32 bx = blockIdx.x;                 // 512 blocks: b(3)|r(2)|m(1)|n(3)
    const u32 n0 = (bx & 7u) * 128u;
    const u32 m0 = ((bx >> 3) & 1u) * 128u;
    const u32 r  = (bx >> 4) & 3u;
    const u32 b  = bx >> 6;
    const u16* pA = Wt + (size_t)r * 65536u + (size_t)m0 * 256u;
    const u16* pB = textb + (size_t)b * 262144u + (size_t)n0 * 256u;
    f32x4 acc[4][4];
#pragma unroll
    for (int i = 0; i < 4; ++i)
#pragma unroll
        for (int j = 0; j < 4; ++j) acc[i][j] = (f32x4){0.f, 0.f, 0.f, 0.f};
    gemm_core<8>(pA, 256u, pB, 256u, smem, acc);

    const u32 lane = threadIdx.x & 63u, w = threadIdx.x >> 6;
    const u32 wm = (w >> 1) * 64u, wn = (w & 1u) * 64u;
    const u32 rit = (lane >> 4) * 4u, cit = lane & 15u;  // C: row=(lane>>4)*4+reg
    u16* yb = Yt + (size_t)(b * 4u + r) * 262144u;
#pragma unroll
    for (int mt = 0; mt < 4; ++mt)
#pragma unroll
        for (int nt = 0; nt < 4; ++nt) {
            const u32 m = m0 + wm + (u32)mt * 16u + rit;
            const u32 n = n0 + wn + (u32)nt * 16u + cit;
#pragma unroll
            for (int rg = 0; rg < 4; ++rg)
                yb[(size_t)(m + (u32)rg) * 1024u + n] = f2b(acc[mt][nt][rg]);
        }
}

// Fused: partial[b,r,i,d] = inv[b,r,i] * sum_j adj[b,r,i,j]*Yt[b,r,d,j]
// where inv = 1/rowsum_fp32(adj row), computed during staging.
//
// 64x128 block tile (M-split 16) -> 1024 blocks = 4 blocks/CU = 16 waves/CU:
// cross-block TLP is the primary latency hider. Depth-2 counted-vmcnt
// pipeline (T3/T4) on top: per steady-state iteration, exactly 4 VMEM ops
// are issued (2x A float4 + 2x B global_load_lds, both for tile ks+2); the
// end-of-iter wait is s_waitcnt vmcnt(4) — drain everything EXCEPT this
// iteration's 4 — so tile ks+1's loads are landed and tile ks+2's stay in
// flight across the barrier. No drain-to-0 in the main loop.
// Invariant entering iter ks: bufA[ks&1]=A(ks), bufB[ks%3]=B(ks),
// rA[(ks+1)&1]=A(ks+1) regs; outstanding VMEM = {A(ks+1)x2, B(ks+1)x2}.
__global__ __launch_bounds__(256) void adj_gemm_fused(const float* adj, const u16* Yt,
                                                      float* partial) {
    __shared__ char smem[33024];
    // bufA[2] @ 0, 4096 ; bufB[3] @ 8192, 16384, 24576 ; sInv @ 32768
    float* sInv = (float*)(smem + 32768);

    // XCD-contiguous bijective remap (1024 = 8 XCDs x 128): blocks sharing
    // adj row-panels and Yt panels co-reside on one XCD's L2.
    const u32 bxRaw = blockIdx.x;
    const u32 bx = (bxRaw & 7u) * 128u + (bxRaw >> 3);

    const u32 n0 = (bx & 1u) * 128u;          // d_out half
    const u32 m0 = ((bx >> 1) & 15u) * 64u;   // i tile
    const u32 r  = (bx >> 5) & 3u;
    const u32 b  = bx >> 7;

    const float* pA = adj + (size_t)(b * 4u + r) * 1048576u + (size_t)m0 * 1024u;
    const u16*   pB = Yt + (size_t)(b * 4u + r) * 262144u + (size_t)n0 * 1024u;

    const u32 t    = threadIdx.x;
    const u32 lane = t & 63u;
    const u32 w    = t >> 6;
    const u32 wm   = (w >> 1) * 32u;          // wave tile 32x64
    const u32 wn   = (w & 1u) * 64u;
    const u32 waveByte = (t & 192u) * 16u;
    const u32 rowA = t >> 2;                  // 0..63 (A row; also B row half 0)
    const u32 ggA  = (t & 3u) ^ ((rowA >> 1) & 3u);
    const u32 rowB1 = rowA + 64u;             // B rows 64..127
    const u32 ggB1  = ((t + 256u) & 3u) ^ ((rowB1 >> 1) & 3u);
    const u32 fr = lane & 15u;
    const u32 fg = lane >> 4;

    f32x4 acc[2][4];
#pragma unroll
    for (int i = 0; i < 2; ++i)
#pragma unroll
        for (int j = 0; j < 4; ++j) acc[i][j] = (f32x4){0.f, 0.f, 0.f, 0.f};

    const float* rp0 = pA + (size_t)rowA * 1024u + ggA * 8u;

    float s0 = 0.f;
    float4 rA[2][2];   // two A register sets; indices fold under unroll

    auto do_mfma = [&](char* curA, char* curB) {
        bf16_8 af[2], bfv[4];
#pragma unroll
        for (int mt = 0; mt < 2; ++mt) {
            uint4 v = *(const uint4*)(curA + swz_off(wm + (u32)mt * 16u + fr, fg));
            af[mt] = __builtin_bit_cast(bf16_8, v);
        }
#pragma unroll
        for (int nt = 0; nt < 4; ++nt) {
            uint4 v = *(const uint4*)(curB + swz_off(wn + (u32)nt * 16u + fr, fg));
            bfv[nt] = __builtin_bit_cast(bf16_8, v);
        }
#pragma unroll
        for (int mt = 0; mt < 2; ++mt)
#pragma unroll
            for (int nt = 0; nt < 4; ++nt)
                acc[mt][nt] = __builtin_amdgcn_mfma_f32_16x16x32_bf16(af[mt], bfv[nt],
                                                                      acc[mt][nt], 0, 0, 0);
    };
    auto pack_to = [&](const float4* rs, char* dst) {
        const float4 a0 = rs[0], a1 = rs[1];
        s0 += (a0.x + a0.y + a0.z + a0.w) + (a1.x + a1.y + a1.z + a1.w);
        *(uint4*)(dst + t * 16u) = pack8(a0, a1);   // linear == swizzled slot
    };

    // ---- Prologue ----
    // Group 1: A(0) -> rA[0], B(0) -> bufB0      (4 ops, oldest)
    rA[0][0] = *(const float4*)(rp0);
    rA[0][1] = *(const float4*)(rp0 + 4);
    gload_lds16(pB + (size_t)rowA * 1024u + ggA * 8u, smem + 8192u + waveByte);
    gload_lds16(pB + (size_t)rowB1 * 1024u + ggB1 * 8u, smem + 8192u + waveByte + 4096u);
    memfence_sched();
    // Group 2: A(1) -> rA[1], B(1) -> bufB1      (4 ops, newest)
    rA[1][0] = *(const float4*)(rp0 + 32u);
    rA[1][1] = *(const float4*)(rp0 + 36u);
    gload_lds16(pB + (size_t)rowA * 1024u + 32u + ggA * 8u, smem + 16384u + waveByte);
    gload_lds16(pB + (size_t)rowB1 * 1024u + 32u + ggB1 * 8u, smem + 16384u + waveByte + 4096u);
    memfence_sched();
    // Pack A(0) -> bufA0 (compiler-inserted wait drains A(0) loads).
    pack_to(rA[0], smem);
    // Drain B(0) too: keep only the newest 4 (= group 2) outstanding.
    asm volatile("s_waitcnt vmcnt(4) lgkmcnt(0)" ::: "memory");
    __builtin_amdgcn_s_barrier();

    // ---- Main loop: iterations 0..29 (compute tile ks; issue tile ks+2) ----
#pragma unroll 6
    for (int ks = 0; ks < 30; ++ks) {
        const int cA = ks & 1;         // folds under unroll (6 % 2 == 0)
        const int nA = cA ^ 1;
        char* bufAc = smem + (u32)cA * 4096u;
        char* bufAn = smem + (u32)nA * 4096u;
        char* bufBc = smem + 8192u + (u32)(ks % 3) * 8192u;
        char* bufBn = smem + 8192u + (u32)((ks + 2) % 3) * 8192u;

        // Pack A(ks+1) (regs landed; compiler wait leaves B(ks+1) in flight).
        pack_to(rA[nA], bufAn);

        // Issue tile ks+2: 2x A float4 + 2x B gload_lds (exactly 4 VMEM ops).
        const u32 k2 = (u32)(ks + 2) * 32u;
        rA[cA][0] = *(const float4*)(rp0 + k2);
        rA[cA][1] = *(const float4*)(rp0 + k2 + 4u);
        gload_lds16(pB + (size_t)rowA * 1024u + k2 + ggA * 8u, bufBn + waveByte);
        gload_lds16(pB + (size_t)rowB1 * 1024u + k2 + ggB1 * 8u, bufBn + waveByte + 4096u);

        // Compute tile ks while ks+2's loads fly.
        do_mfma(bufAc, bufBc);

        // Drain everything except this iter's 4 ops -> B(ks+1) landed,
        // A ds_writes visible; tile ks+2's loads stay in flight.
        asm volatile("s_waitcnt vmcnt(4) lgkmcnt(0)" ::: "memory");
        __builtin_amdgcn_s_barrier();
    }

    // ---- Peeled iter 30: pack A(31), no new issues ----
    pack_to(rA[1], smem + 4096u);            // A(31) -> bufA1
    do_mfma(smem + 0u, smem + 8192u);        // tile 30: bufA0, bufB[30%3=0]
    asm volatile("s_waitcnt vmcnt(0) lgkmcnt(0)" ::: "memory");  // drain B(31)
    __builtin_amdgcn_s_barrier();

    // ---- Peeled iter 31 ----
    do_mfma(smem + 4096u, smem + 16384u);    // tile 31: bufA1, bufB[31%3=1]

    // rowsum: 4 consecutive lanes (t&3) hold partials of the same row
    s0 += __shfl_down(s0, 2, 64); s0 += __shfl_down(s0, 1, 64);
    if ((t & 3u) == 0u) {
        sInv[rowA] = (s0 == 0.f) ? 0.f : 1.f / s0;
    }
    __syncthreads();

    const u32 rit = (lane >> 4) * 4u, cit = lane & 15u;
    float* pp = partial + (size_t)(b * 4u + r) * 262144u;
#pragma unroll
    for (int mt = 0; mt < 2; ++mt) {
        const u32 mBase = wm + (u32)mt * 16u + rit;
        float sv[4];
#pragma unroll
        for (int rg = 0; rg < 4; ++rg) sv[rg] = sInv[mBase + (u32)rg];
#pragma unroll
        for (int nt = 0; nt < 4; ++nt) {
            const u32 n = n0 + wn + (u32)nt * 16u + cit;
#pragma unroll
            for (int rg = 0; rg < 4; ++rg)
                pp[(size_t)(m0 + mBase + (u32)rg) * 256u + n] = acc[mt][nt][rg] * sv[rg];
        }
    }
}

// out[b,i,d] = bias[d] + sum_r partial[b,r,i,d]
__global__ __launch_bounds__(256) void reduce_kernel(const float* partial,
                                                     const float* bias, float* out) {
    const u32 i4 = blockIdx.x * 256u + threadIdx.x;  // 524288 threads, 4 f32 each
    const u32 base = i4 * 4u;
    const u32 b = base >> 18;
    const u32 rem = base & 262143u;
    float4 s = ((const float4*)bias)[i4 & 63u];
#pragma unroll
    for (u32 r = 0; r < 4; ++r) {
        const float4 v = *(const float4*)(partial + (((size_t)(b * 4u + r)) << 18) + rem);
        s.x += v.x; s.y += v.y; s.z += v.z; s.w += v.w;
    }
    ((float4*)out)[i4] = s;
}

extern "C" void kernel_launch(void* const* d_in, const int* in_sizes, int n_in,
                              void* d_out, int out_size, void* d_ws, size_t ws_size,
                              hipStream_t stream) {
    const float* text = (const float*)d_in[0];  // [8,1024,256] fp32
    const float* adj  = (const float*)d_in[1];  // [8,4,1024,1024] fp32
    const float* wgt  = (const float*)d_in[2];  // [4,256,256] fp32
    const float* bias = (const float*)d_in[3];  // [256] fp32
    float* out = (float*)d_out;                 // [8,1024,256] fp32

    char* ws = (char*)d_ws;
    u16* Yt        = (u16*)ws;                      // 16 MB  bf16 [B,R,256,1024]
    u16* textb     = (u16*)(ws + 16777216u);        //  4 MB  bf16 [B,N,256]
    u16* Wt        = (u16*)(ws + 20971520u);        // 512 KB bf16 [R,256,256]
    float* partial = (float*)(ws + 21495808u);      // 32 MB  fp32 [B,R,N,256]

    text_cvt_kernel<<<1024, 256, 0, stream>>>(text, textb);
    wt_cvt_kernel<<<1024, 256, 0, stream>>>(wgt, Wt);
    y_gemm_kernel<<<512, 256, 0, stream>>>(Wt, textb, Yt);
    adj_gemm_fused<<<1024, 256, 0, stream>>>(adj, Yt, partial);
    reduce_kernel<<<2048, 256, 0, stream>>>(partial, bias, out);
}

// Round 5
// 67.090 us; speedup vs baseline: 1.2435x; 1.0199x over previous
//
#include <hip/hip_runtime.h>
#include <hip/hip_bf16.h>
#include <stdint.h>

typedef __bf16 bf16_8 __attribute__((ext_vector_type(8)));
typedef float f32x4 __attribute__((ext_vector_type(4)));
typedef unsigned int u32;
typedef unsigned short u16;

// Problem dims (fixed): B=8, R=4, N=1024, D_IN=D_OUT=256.
// Inputs FP32 (per reference); internal GEMMs bf16 MFMA; output FP32.

__device__ __forceinline__ u16 f2b(float f) {
    return __builtin_bit_cast(u16, __float2bfloat16(f));
}

// LDS tile: rows x 32 k (bf16) as 16B chunks, 4 chunks/row.
// Chunk (row,g) at index row*4 + (g ^ ((row>>1)&3)) -> frag reads (fixed g,
// 16 consecutive rows) stay <=2-way bank conflicted (free per m136).
__device__ __forceinline__ u32 swz_off(u32 row, u32 g) {
    return (row * 4u + (g ^ ((row >> 1) & 3u))) * 16u;
}

__device__ __forceinline__ void gload_lds16(const void* g, void* l) {
    __builtin_amdgcn_global_load_lds((const __attribute__((address_space(1))) void*)g,
                                     (__attribute__((address_space(3))) void*)l, 16, 0, 0);
}

// Compiler-only memory scheduling fence: pins VMEM issue-order regions so
// counted s_waitcnt vmcnt(N) bookkeeping is deterministic.
__device__ __forceinline__ void memfence_sched() { asm volatile("" ::: "memory"); }

__device__ __forceinline__ uint4 pack8(float4 a, float4 b) {
    uint4 pk;
    pk.x = (u32)f2b(a.x) | ((u32)f2b(a.y) << 16);
    pk.y = (u32)f2b(a.z) | ((u32)f2b(a.w) << 16);
    pk.z = (u32)f2b(b.x) | ((u32)f2b(b.y) << 16);
    pk.w = (u32)f2b(b.z) | ((u32)f2b(b.w) << 16);
    return pk;
}

// C[128x128] += A[128xK]*B[Kx128]; used by y_gemm only (small, ~3us).
template <int KSTEPS>
__device__ __forceinline__ void gemm_core(const u16* pA, u32 strideA,
                                          const u16* pB, u32 strideB,
                                          char* smem, f32x4 acc[4][4]) {
    const u32 t    = threadIdx.x;
    const u32 lane = t & 63u;
    const u32 w    = t >> 6;
    const u32 wm   = (w >> 1) * 64u;
    const u32 wn   = (w & 1u) * 64u;
    const u32 waveByte = (t & 192u) * 16u;
    const u32 row0 = t >> 2;
    const u32 gg0  = (t & 3u) ^ ((row0 >> 1) & 3u);
    const u32 row1 = row0 + 64u;
    const u32 gg1  = ((t + 256u) & 3u) ^ ((row1 >> 1) & 3u);
    const u32 fr = lane & 15u;
    const u32 fg = lane >> 4;

    gload_lds16(pA + (size_t)row0 * strideA + gg0 * 8u, smem + waveByte);
    gload_lds16(pA + (size_t)row1 * strideA + gg1 * 8u, smem + waveByte + 4096u);
    gload_lds16(pB + (size_t)row0 * strideB + gg0 * 8u, smem + 16384u + waveByte);
    gload_lds16(pB + (size_t)row1 * strideB + gg1 * 8u, smem + 16384u + waveByte + 4096u);
    asm volatile("s_waitcnt vmcnt(0)" ::: "memory");
    __builtin_amdgcn_s_barrier();

    u32 c = 0;
#pragma unroll 2
    for (int ks = 0; ks < KSTEPS; ++ks) {
        char* curA = smem + c * 8192u;
        char* curB = smem + 16384u + c * 8192u;
        if (ks + 1 < KSTEPS) {
            char* nxtA = smem + (c ^ 1u) * 8192u;
            char* nxtB = smem + 16384u + (c ^ 1u) * 8192u;
            const u32 k0 = (u32)(ks + 1) * 32u;
            gload_lds16(pA + (size_t)row0 * strideA + k0 + gg0 * 8u, nxtA + waveByte);
            gload_lds16(pA + (size_t)row1 * strideA + k0 + gg1 * 8u, nxtA + waveByte + 4096u);
            gload_lds16(pB + (size_t)row0 * strideB + k0 + gg0 * 8u, nxtB + waveByte);
            gload_lds16(pB + (size_t)row1 * strideB + k0 + gg1 * 8u, nxtB + waveByte + 4096u);
        }

        bf16_8 af[4], bfv[4];
#pragma unroll
        for (int mt = 0; mt < 4; ++mt) {
            uint4 v = *(const uint4*)(curA + swz_off(wm + (u32)mt * 16u + fr, fg));
            af[mt] = __builtin_bit_cast(bf16_8, v);
        }
#pragma unroll
        for (int nt = 0; nt < 4; ++nt) {
            uint4 v = *(const uint4*)(curB + swz_off(wn + (u32)nt * 16u + fr, fg));
            bfv[nt] = __builtin_bit_cast(bf16_8, v);
        }
#pragma unroll
        for (int mt = 0; mt < 4; ++mt)
#pragma unroll
            for (int nt = 0; nt < 4; ++nt)
                acc[mt][nt] = __builtin_amdgcn_mfma_f32_16x16x32_bf16(af[mt], bfv[nt],
                                                                      acc[mt][nt], 0, 0, 0);

        if (ks + 1 < KSTEPS) {
            asm volatile("s_waitcnt vmcnt(0)" ::: "memory");
            __builtin_amdgcn_s_barrier();
        }
        c ^= 1u;
    }
}

// textb = bf16(text), layout preserved [B,N,D_in]. 8 elems/thread.
__global__ __launch_bounds__(256) void text_cvt_kernel(const float* t, u16* tb) {
    const u32 i8 = blockIdx.x * 256u + threadIdx.x;  // 262144 total
    const float4 a = ((const float4*)t)[i8 * 2u];
    const float4 b = ((const float4*)t)[i8 * 2u + 1u];
    ((uint4*)tb)[i8] = pack8(a, b);
}

// Wt[r][dout][din] = bf16(W[r][din][dout])
__global__ __launch_bounds__(256) void wt_cvt_kernel(const float* W, u16* Wt) {
    const u32 idx = blockIdx.x * 256u + threadIdx.x;  // 262144 total
    const u32 r = idx >> 16, rem = idx & 65535u, dout = rem >> 8, din = rem & 255u;
    Wt[idx] = f2b(W[(r << 16) + (din << 8) + dout]);
}

// Yt[b,r,dout,j] = bf16( sum_din Wt[r,dout,din] * textb[b,j,din] )
__global__ __launch_bounds__(256) void y_gemm_kernel(const u16* Wt, const u16* textb,
                                                     u16* Yt) {
    __shared__ char smem[32768];
    const u32 bx = blockIdx.x;                 // 512 blocks: b(3)|r(2)|m(1)|n(3)
    const u32 n0 = (bx & 7u) * 128u;
    const u32 m0 = ((bx >> 3) & 1u) * 128u;
    const u32 r  = (bx >> 4) & 3u;
    const u32 b  = bx >> 6;
    const u16* pA = Wt + (size_t)r * 65536u + (size_t)m0 * 256u;
    const u16* pB = textb + (size_t)b * 262144u + (size_t)n0 * 256u;
    f32x4 acc[4][4];
#pragma unroll
    for (int i = 0; i < 4; ++i)
#pragma unroll
        for (int j = 0; j < 4; ++j) acc[i][j] = (f32x4){0.f, 0.f, 0.f, 0.f};
    gemm_core<8>(pA, 256u, pB, 256u, smem, acc);

    const u32 lane = threadIdx.x & 63u, w = threadIdx.x >> 6;
    const u32 wm = (w >> 1) * 64u, wn = (w & 1u) * 64u;
    const u32 rit = (lane >> 4) * 4u, cit = lane & 15u;  // C: row=(lane>>4)*4+reg
    u16* yb = Yt + (size_t)(b * 4u + r) * 262144u;
#pragma unroll
    for (int mt = 0; mt < 4; ++mt)
#pragma unroll
        for (int nt = 0; nt < 4; ++nt) {
            const u32 m = m0 + wm + (u32)mt * 16u + rit;
            const u32 n = n0 + wn + (u32)nt * 16u + cit;
#pragma unroll
            for (int rg = 0; rg < 4; ++rg)
                yb[(size_t)(m + (u32)rg) * 1024u + n] = f2b(acc[mt][nt][rg]);
        }
}

// partial[b,r,i,d] = inv[b,r,i] * sum_j adj[b,r,i,j]*Yt[b,r,d,j]
//
// ADJ-ONCE geometry: block tile = 64 i-rows x FULL d=256, K=1024.
// Grid 512 = 8b x 4r x 16 i-tiles -> each adj element is read by exactly
// ONE block (adj traffic 268->134 MB). Yt panel (512 KB) is re-read by the
// 16 same-(b,r) blocks, which the XCD remap makes co-resident on one XCD
// (Yt per XCD = 2 MB < 4 MB L2) -> Yt traffic is L2-tier.
// 512 threads = 8 waves; wave w: rows [16*(w>>1), +16), cols [128*(w&1), +128).
// Depth-2 counted-vmcnt pipeline (proven R2/R3 skeleton): per steady iter
// exactly 3 VMEM ops (1x A float4 + 2x B gload_lds, both tile ks+2);
// end-of-iter wait = vmcnt(3) -> tile ks+1 landed, ks+2 stays in flight.
// Invariant entering iter ks: bufA[ks&1]=A(ks), bufB[ks%3]=B(ks),
// rA[(ks+1)&1]=A(ks+1) regs; outstanding = {A(ks+1)x1, B(ks+1)x2}.
__global__ __launch_bounds__(512, 4) void adj_gemm_partial(const float* adj,
                                                           const u16* Yt,
                                                           float* partial) {
    __shared__ char smem[57600];
    char* bufA = smem;                     // 2 x 4096  (64 rows x 32k bf16)
    char* bufB = smem + 8192;              // 3 x 16384 (256 rows x 32k bf16)
    float* sInv = (float*)(smem + 57344);  // 64 row inverses

    // XCD-contiguous bijective remap (512 = 8 XCDs x 64): XCD x gets batch
    // b = x entirely; the 16 blocks sharing a Yt panel are co-XCD.
    const u32 raw = blockIdx.x;
    const u32 bx = (raw & 7u) * 64u + (raw >> 3);

    const u32 i0 = (bx & 15u) * 64u;
    const u32 r  = (bx >> 4) & 3u;
    const u32 b  = bx >> 6;

    const float* pA = adj + (size_t)(b * 4u + r) * 1048576u + (size_t)i0 * 1024u;
    const u16*   pB = Yt + (size_t)(b * 4u + r) * 262144u;

    const u32 t    = threadIdx.x;
    const u32 lane = t & 63u;
    const u32 w    = t >> 6;
    const u32 wi   = (w >> 1) * 16u;      // wave i-base (0..48)
    const u32 wd   = (w & 1u) * 128u;     // wave d-base (0/128)
    const u32 fr   = lane & 15u;
    const u32 fg   = lane >> 4;

    // A staging map: thread t loads 4 f32 (one float4) of tile row arow.
    // Pre-swizzled source so the LINEAR ds_write_b64 slot t holds the chunk
    // the swizzled frag-read expects (involution: both sides use swz_off).
    const u32 arow = t >> 3;                              // 0..63
    const u32 acg  = ((t >> 1) & 3u) ^ ((arow >> 1) & 3u);
    const float* aPtr = pA + (size_t)arow * 1024u + acg * 8u + (t & 1u) * 4u;

    // B staging map: 1024 16B-chunk slots, thread t stages slots t, t+512
    // via gload_lds (linear LDS dst = wave base + lane*16); global source
    // pre-swizzled per row.
    const u32 brow0 = t >> 2;                             // 0..127
    const u32 brow1 = (t + 512u) >> 2;                    // 128..255
    const u32 bcg0  = (t & 3u) ^ ((brow0 >> 1) & 3u);
    const u32 bcg1  = (t & 3u) ^ ((brow1 >> 1) & 3u);
    const u16* bPtr0 = pB + (size_t)brow0 * 1024u + bcg0 * 8u;
    const u16* bPtr1 = pB + (size_t)brow1 * 1024u + bcg1 * 8u;
    const u32 waveB = (t & 448u) * 16u;   // wave-uniform LDS byte base

    f32x4 acc[8];
#pragma unroll
    for (int i = 0; i < 8; ++i) acc[i] = (f32x4){0.f, 0.f, 0.f, 0.f};

    float s0 = 0.f;
    float4 rA[2];

    auto stageB = [&](u32 kt, char* dst) {
        gload_lds16(bPtr0 + kt * 32u, dst + waveB);
        gload_lds16(bPtr1 + kt * 32u, dst + 8192u + waveB);
    };
    auto packA = [&](float4 a, char* dst) {
        s0 += (a.x + a.y) + (a.z + a.w);
        uint2 pk;
        pk.x = (u32)f2b(a.x) | ((u32)f2b(a.y) << 16);
        pk.y = (u32)f2b(a.z) | ((u32)f2b(a.w) << 16);
        *(uint2*)(dst + t * 8u) = pk;
    };
    auto do_mfma = [&](char* curA, char* curB) {
        uint4 va = *(const uint4*)(curA + swz_off(wi + fr, fg));
        bf16_8 af = __builtin_bit_cast(bf16_8, va);
#pragma unroll
        for (int nt = 0; nt < 8; ++nt) {
            uint4 v = *(const uint4*)(curB + swz_off(wd + (u32)nt * 16u + fr, fg));
            bf16_8 bfv = __builtin_bit_cast(bf16_8, v);
            acc[nt] = __builtin_amdgcn_mfma_f32_16x16x32_bf16(af, bfv, acc[nt], 0, 0, 0);
        }
    };

    // ---- Prologue ----
    rA[0] = *(const float4*)(aPtr);            // A(0)  (1 op)
    stageB(0u, bufB);                          // B(0)  (2 ops)
    memfence_sched();
    rA[1] = *(const float4*)(aPtr + 32u);      // A(1)  (1 op)
    stageB(1u, bufB + 16384u);                 // B(1)  (2 ops)
    memfence_sched();
    packA(rA[0], bufA);                        // compiler wait drains A(0)
    asm volatile("s_waitcnt vmcnt(3) lgkmcnt(0)" ::: "memory");  // B(0) landed
    __builtin_amdgcn_s_barrier();

    // ---- Main loop: iters 0..29 (compute tile ks; issue tile ks+2) ----
#pragma unroll 6
    for (int ks = 0; ks < 30; ++ks) {
        const int cA = ks & 1;                 // folds under unroll 6
        const int nA = cA ^ 1;

        packA(rA[nA], bufA + (u32)nA * 4096u); // A(ks+1) -> LDS
        rA[cA] = *(const float4*)(aPtr + (u32)(ks + 2) * 32u);        // 1 op
        stageB((u32)(ks + 2), bufB + (u32)((ks + 2) % 3) * 16384u);   // 2 ops

        do_mfma(bufA + (u32)cA * 4096u, bufB + (u32)(ks % 3) * 16384u);

        asm volatile("s_waitcnt vmcnt(3) lgkmcnt(0)" ::: "memory");
        __builtin_amdgcn_s_barrier();
    }

    // ---- Peeled iter 30: pack A(31), no new issues ----
    packA(rA[1], bufA + 4096u);
    do_mfma(bufA, bufB);                       // tile 30: bufA0, bufB[30%3=0]
    asm volatile("s_waitcnt vmcnt(0) lgkmcnt(0)" ::: "memory");
    __builtin_amdgcn_s_barrier();

    // ---- Peeled iter 31 ----
    do_mfma(bufA + 4096u, bufB + 16384u);      // tile 31: bufA1, bufB[31%3=1]

    // rowsum: 8 consecutive threads (t&7) hold partials of row t>>3
    s0 += __shfl_down(s0, 4, 64);
    s0 += __shfl_down(s0, 2, 64);
    s0 += __shfl_down(s0, 1, 64);
    if ((t & 7u) == 0u) sInv[arow] = (s0 == 0.f) ? 0.f : 1.f / s0;
    __syncthreads();

    const u32 rit = fg * 4u;                   // C row = (lane>>4)*4 + reg
    float* pp = partial + (size_t)(b * 4u + r) * 262144u + (size_t)i0 * 256u;
#pragma unroll
    for (int rg = 0; rg < 4; ++rg) {
        const u32 mRow = wi + rit + (u32)rg;
        const float inv = sInv[mRow];
#pragma unroll
        for (int nt = 0; nt < 8; ++nt)
            pp[(size_t)mRow * 256u + wd + (u32)nt * 16u + fr] = acc[nt][rg] * inv;
    }
}

// out[b,i,d] = bias[d] + sum_r partial[b,r,i,d]
__global__ __launch_bounds__(256) void reduce_kernel(const float* partial,
                                                     const float* bias, float* out) {
    const u32 i4 = blockIdx.x * 256u + threadIdx.x;  // 524288 threads, 4 f32 each
    const u32 base = i4 * 4u;
    const u32 b = base >> 18;
    const u32 rem = base & 262143u;
    float4 s = ((const float4*)bias)[i4 & 63u];
#pragma unroll
    for (u32 r = 0; r < 4; ++r) {
        const float4 v = *(const float4*)(partial + (((size_t)(b * 4u + r)) << 18) + rem);
        s.x += v.x; s.y += v.y; s.z += v.z; s.w += v.w;
    }
    ((float4*)out)[i4] = s;
}

extern "C" void kernel_launch(void* const* d_in, const int* in_sizes, int n_in,
                              void* d_out, int out_size, void* d_ws, size_t ws_size,
                              hipStream_t stream) {
    const float* text = (const float*)d_in[0];  // [8,1024,256] fp32
    const float* adj  = (const float*)d_in[1];  // [8,4,1024,1024] fp32
    const float* wgt  = (const float*)d_in[2];  // [4,256,256] fp32
    const float* bias = (const float*)d_in[3];  // [256] fp32
    float* out = (float*)d_out;                 // [8,1024,256] fp32

    char* ws = (char*)d_ws;
    u16* Yt        = (u16*)ws;                      // 16 MB  bf16 [B,R,256,1024]
    u16* textb     = (u16*)(ws + 16777216u);        //  4 MB  bf16 [B,N,256]
    u16* Wt        = (u16*)(ws + 20971520u);        // 512 KB bf16 [R,256,256]
    float* partial = (float*)(ws + 21495808u);      // 32 MB  fp32 [B,R,N,256]

    text_cvt_kernel<<<1024, 256, 0, stream>>>(text, textb);
    wt_cvt_kernel<<<1024, 256, 0, stream>>>(wgt, Wt);
    y_gemm_kernel<<<512, 256, 0, stream>>>(Wt, textb, Yt);
    adj_gemm_partial<<<512, 512, 0, stream>>>(adj, Yt, partial);
    reduce_kernel<<<2048, 256, 0, stream>>>(partial, bias, out);
}